// Round 3
// baseline (124.242 us; speedup 1.0000x reference)
//
#include <hip/hip_runtime.h>

// Chamfer distance, B=16, N=M=4096, 2-D fp32 points, prefix-length masks.
// d_out: [fwd 16*4096][bwd 16*4096] fp32.
//
// R3: v_dot2_f32_f16 (1 full-rate instr = 2-elem f16 dot + f32 acc) computes
// t2 - 2*q.t per pair; v_min3_f32 merges 2 points per min. 1.5 VALU/pair vs 6.
// Rounding q,t to f16 consistently (s2,t2 from rounded coords) => computed
// value is |q_h - t_h|^2 exactly; output err ~ coord rounding <= ~6e-3 << 3.2e-2.
// LDS: 2 points per ds_read_b128 (half2 bits + f32 t2 each).
// Fused finalize: bits + per-row counters in d_ws (memset 0xFF; counter wraps
// 0xFFFFFFFF->0 on first inc, 16th incrementer sees old==14). Last chunk-block
// per (dir,b) row does sqrt+mask into d_out. Finalizer reads via
// atomicMin(p,0xFFFFFFFF) = device-scope atomic read, same coherence path as
// the atomicMin writes (safe under XCD L2 non-coherence).

#define NQ 16
typedef _Float16 h2 __attribute__((ext_vector_type(2)));

#if defined(__has_builtin)
#  if __has_builtin(__builtin_amdgcn_fdot2)
#    define FDOT2(a, b, c) __builtin_amdgcn_fdot2((a), (b), (c), false)
#  endif
#endif
#ifndef FDOT2  // correct-but-slower fallback if builtin is unavailable
#  define FDOT2(a, b, c) fmaf((float)(a)[0], (float)(b)[0], fmaf((float)(a)[1], (float)(b)[1], (c)))
#endif

__global__ __launch_bounds__(256, 2) void chamfer_main(
    const float* __restrict__ src, const float* __restrict__ tgt,
    const int* __restrict__ slen, const int* __restrict__ tlen,
    unsigned int* __restrict__ ws_bits,    // [131072] min-d2 bits, pre-memset 0xFF
    unsigned int* __restrict__ counters,   // [32] per-row, pre-memset 0xFF
    float* __restrict__ out)               // [131072] final output
{
    __shared__ float4 sh[128];   // 2 staged points per float4: (bits(h2), t2, bits(h2), t2)
    __shared__ int last_flag;

    const int bx  = blockIdx.x;
    const int dir = bx >> 8;         // 0: fwd (query=src, search tgt), 1: bwd
    const int b   = (bx >> 4) & 15;  // batch
    const int pc  = bx & 15;         // search-point chunk (256 points)
    const int tid = threadIdx.x;

    const float* Q = dir ? tgt : src;
    const float* P = dir ? src : tgt;
    const int Lq = dir ? tlen[b] : slen[b];   // query-side valid length
    const int Lp = dir ? slen[b] : tlen[b];   // search-side valid length

    int count = Lp - pc * 256;
    count = count < 0 ? 0 : (count > 256 ? 256 : count);

    const int row = dir * 16 + b;
    unsigned int* bits_row = ws_bits + row * 4096;

    if (count > 0) {   // block-uniform branch (barrier inside is safe)
        // Stage 256 points: f16-rounded coords + t2 from the ROUNDED coords.
        {
            const float2 p = ((const float2*)P)[b * 4096 + pc * 256 + tid];
            h2 th; float t2;
            if (tid < count) {
                th = h2{(_Float16)p.x, (_Float16)p.y};
                const float txf = (float)th[0], tyf = (float)th[1];
                t2 = fmaf(txf, txf, tyf * tyf);
            } else {
                th = h2{(_Float16)0.f, (_Float16)0.f};
                t2 = 1e30f;                      // poison: never wins the min
            }
            ((float2*)sh)[tid] = make_float2(__builtin_bit_cast(float, th), t2);
        }
        __syncthreads();

        // 16 queries/thread (whole 4096-row), f16-rounded, s2 from rounded coords.
        h2 qh[NQ]; float s2[NQ], best[NQ];
        #pragma unroll
        for (int k = 0; k < NQ; ++k) {
            const float2 q = ((const float2*)Q)[b * 4096 + tid + k * 256];
            const _Float16 qx = (_Float16)q.x, qy = (_Float16)q.y;
            const float qxf = (float)qx, qyf = (float)qy;
            s2[k]   = fmaf(qxf, qxf, qyf * qyf);
            qh[k]   = h2{(_Float16)(-2.0f * qxf), (_Float16)(-2.0f * qyf)};
            best[k] = 3.0e38f;
        }

        // Inner loop: per 2 points x 16 queries: 1 ds_read_b128 + 32 dot2 + 16 min3.
        #pragma unroll 2
        for (int j = 0; j < 128; ++j) {
            const float4 td = sh[j];
            const h2 th0 = __builtin_bit_cast(h2, td.x);
            const h2 th1 = __builtin_bit_cast(h2, td.z);
            #pragma unroll
            for (int k = 0; k < NQ; ++k) {
                const float v0 = FDOT2(qh[k], th0, td.y);   // t2 - 2*q.t
                const float v1 = FDOT2(qh[k], th1, td.w);
                best[k] = fminf(best[k], fminf(v0, v1));    // fuses to v_min3_f32
            }
        }

        #pragma unroll
        for (int k = 0; k < NQ; ++k) {
            const float d2 = fmaxf(best[k] + s2[k], 0.f);   // clamp commutes with min
            atomicMin(&bits_row[tid + k * 256], __float_as_uint(d2));
        }
    }

    // Row-completion counting; EVERY block (even count==0) increments.
    __threadfence();   // release: drain our atomicMins before the counter add
    if (tid == 0) {
        const unsigned int old = atomicAdd(&counters[row], 1u);
        last_flag = (old == 14u);   // memset 0xFF: 1st inc returns 0xFFFFFFFF (wraps), 16th returns 14
    }
    __syncthreads();

    if (last_flag) {   // we are the last of 16 chunk-blocks for this row: finalize
        #pragma unroll
        for (int k = 0; k < NQ; ++k) {
            const int i = tid + k * 256;
            // atomic read (min vs identity): device-scope, same path as the writes
            const unsigned int ubits = atomicMin(&bits_row[i], 0xFFFFFFFFu);
            float r = 0.f;
            if (i < Lq)
                r = (ubits == 0xFFFFFFFFu) ? 100000.0f    // empty search set: sqrt(1e10)
                                           : sqrtf(__uint_as_float(ubits));
            out[row * 4096 + i] = r;
        }
    }
}

extern "C" void kernel_launch(void* const* d_in, const int* in_sizes, int n_in,
                              void* d_out, int out_size, void* d_ws, size_t ws_size,
                              hipStream_t stream) {
    const float* src = (const float*)d_in[0];   // [16,4096,2] f32
    const float* tgt = (const float*)d_in[1];   // [16,4096,2] f32
    const int* slen  = (const int*)d_in[2];     // [16] i32
    const int* tlen  = (const int*)d_in[3];     // [16] i32

    unsigned int* ws_bits  = (unsigned int*)d_ws;        // [131072]
    unsigned int* counters = ws_bits + 131072;           // [32]

    hipMemsetAsync(d_ws, 0xFF, (size_t)(131072 + 32) * 4, stream);
    chamfer_main<<<512, 256, 0, stream>>>(src, tgt, slen, tlen,
                                          ws_bits, counters, (float*)d_out);
}

// Round 4
// 110.830 us; speedup vs baseline: 1.1210x; 1.1210x over previous
//
#include <hip/hip_runtime.h>

// Chamfer distance, B=16, N=M=4096, 2-D fp32 points, prefix-length masks.
// d_out: [fwd 16*4096][bwd 16*4096] fp32.
//
// R4: R3's fused finalize (device-scope __threadfence -> L2 writeback per
// block on multi-XCD gfx950, + 1M cross-XCD atomicMin RMWs) was the 72 us
// stall. Now ZERO atomics/fences: each (dir,b,chunk-of-128) block writes its
// 4096 partial mins to a private ws slice (plain coalesced stores); a reduce
// kernel mins over the nact=ceil(Lp/128) active slices + sqrt + mask. Kernel
// boundary on the stream provides cross-XCD visibility. No ws init needed:
// inactive slices are never read. nact==0 -> 1e10 -> sqrt matches reference.
// Inner math kept from R3: v_dot2_f32_f16 (t2 - 2q.t in 1 instr) + min3,
// 1.5 VALU/pair; f16-consistent rounding (s2,t2 from rounded coords) keeps
// absmax ~8e-3 << 3.2e-2 threshold.
// Chunk=128 (grid 1024, ~528 active blocks ~= 2/CU) fixes R3's imbalance.

#define NQ 16
typedef _Float16 h2 __attribute__((ext_vector_type(2)));

#if defined(__has_builtin)
#  if __has_builtin(__builtin_amdgcn_fdot2)
#    define FDOT2(a, b, c) __builtin_amdgcn_fdot2((a), (b), (c), false)
#  endif
#endif
#ifndef FDOT2  // correct-but-slower fallback
#  define FDOT2(a, b, c) fmaf((float)(a)[0], (float)(b)[0], fmaf((float)(a)[1], (float)(b)[1], (c)))
#endif

__global__ __launch_bounds__(256) void chamfer_main(
    const float* __restrict__ src, const float* __restrict__ tgt,
    const int* __restrict__ slen, const int* __restrict__ tlen,
    float* __restrict__ part)   // [32 rows][32 slices][4096] partial mins
{
    __shared__ float4 sh[64];   // 2 staged points per float4: (bits(h2), t2) x2

    const int bx  = blockIdx.x;
    const int dir = bx >> 9;         // 0: fwd (query=src, search tgt), 1: bwd
    const int b   = (bx >> 5) & 15;  // batch
    const int pc  = bx & 31;         // search-point chunk (128 points)
    const int tid = threadIdx.x;

    const float* Q = dir ? tgt : src;
    const float* P = dir ? src : tgt;
    const int Lp = dir ? slen[b] : tlen[b];   // search-side valid length

    int count = Lp - pc * 128;
    count = count < 0 ? 0 : (count > 128 ? 128 : count);
    if (count == 0) return;          // slice never read by reduce (s >= nact)

    // Stage 128 points: f16-rounded coords + t2 from the ROUNDED coords.
    if (tid < 128) {
        const float2 p = ((const float2*)P)[b * 4096 + pc * 128 + tid];
        h2 th; float t2;
        if (tid < count) {
            th = h2{(_Float16)p.x, (_Float16)p.y};
            const float txf = (float)th[0], tyf = (float)th[1];
            t2 = fmaf(txf, txf, tyf * tyf);
        } else {
            th = h2{(_Float16)0.f, (_Float16)0.f};
            t2 = 1e30f;                      // poison: never wins the min
        }
        ((float2*)sh)[tid] = make_float2(__builtin_bit_cast(float, th), t2);
    }
    __syncthreads();

    // 16 queries/thread (whole 4096-row), f16-rounded consistently.
    h2 qh[NQ]; float s2[NQ], best[NQ];
    #pragma unroll
    for (int k = 0; k < NQ; ++k) {
        const float2 q = ((const float2*)Q)[b * 4096 + tid + k * 256];
        const _Float16 qx = (_Float16)q.x, qy = (_Float16)q.y;
        const float qxf = (float)qx, qyf = (float)qy;
        s2[k]   = fmaf(qxf, qxf, qyf * qyf);
        qh[k]   = h2{(_Float16)(-2.0f * qxf), (_Float16)(-2.0f * qyf)};
        best[k] = 3.0e38f;
    }

    // Per 2 points x 16 queries: 1 ds_read_b128 + 32 dot2 + 16 min3.
    #pragma unroll 2
    for (int j = 0; j < 64; ++j) {
        const float4 td = sh[j];
        const h2 th0 = __builtin_bit_cast(h2, td.x);
        const h2 th1 = __builtin_bit_cast(h2, td.z);
        #pragma unroll
        for (int k = 0; k < NQ; ++k) {
            const float v0 = FDOT2(qh[k], th0, td.y);   // t2 - 2*q.t
            const float v1 = FDOT2(qh[k], th1, td.w);
            best[k] = fminf(best[k], fminf(v0, v1));    // v_min3_f32
        }
    }

    // Plain coalesced stores to this block's private slice. No atomics.
    float* slice = part + ((size_t)(dir * 16 + b) * 32 + pc) * 4096;
    #pragma unroll
    for (int k = 0; k < NQ; ++k)
        slice[tid + k * 256] = fmaxf(best[k] + s2[k], 0.f);  // clamp commutes with min
}

__global__ __launch_bounds__(256) void chamfer_reduce(
    const float* __restrict__ part,
    const int* __restrict__ slen, const int* __restrict__ tlen,
    float* __restrict__ out)
{
    const int t  = blockIdx.x * 256 + threadIdx.x;   // 32768 threads, 4 elems each
    const int i4 = t * 4;
    const int row = i4 >> 12;                        // (dir*16 + b)
    const int dir = row >> 4, b = row & 15;
    const int i   = i4 & 4095;
    const int Lq = dir ? tlen[b] : slen[b];
    const int Lp = dir ? slen[b] : tlen[b];
    const int nact = (Lp + 127) >> 7;                // active slices (block-uniform)

    float4 best = make_float4(1e10f, 1e10f, 1e10f, 1e10f);
    const float4* p = (const float4*)(part + (size_t)row * 32 * 4096 + i);
    for (int s = 0; s < nact; ++s) {
        const float4 v = p[(size_t)s * 1024];        // stride 4096 floats
        best.x = fminf(best.x, v.x);
        best.y = fminf(best.y, v.y);
        best.z = fminf(best.z, v.z);
        best.w = fminf(best.w, v.w);
    }
    float4 r;
    r.x = (i + 0 < Lq) ? sqrtf(best.x) : 0.f;        // nact==0 -> sqrt(1e10), matches ref
    r.y = (i + 1 < Lq) ? sqrtf(best.y) : 0.f;
    r.z = (i + 2 < Lq) ? sqrtf(best.z) : 0.f;
    r.w = (i + 3 < Lq) ? sqrtf(best.w) : 0.f;
    ((float4*)out)[t] = r;
}

extern "C" void kernel_launch(void* const* d_in, const int* in_sizes, int n_in,
                              void* d_out, int out_size, void* d_ws, size_t ws_size,
                              hipStream_t stream) {
    const float* src = (const float*)d_in[0];   // [16,4096,2] f32
    const float* tgt = (const float*)d_in[1];   // [16,4096,2] f32
    const int* slen  = (const int*)d_in[2];     // [16] i32
    const int* tlen  = (const int*)d_in[3];     // [16] i32
    float* part = (float*)d_ws;                 // 32 rows x 32 slices x 4096 f32 = 16 MB

    chamfer_main<<<1024, 256, 0, stream>>>(src, tgt, slen, tlen, part);
    chamfer_reduce<<<128, 256, 0, stream>>>(part, slen, tlen, (float*)d_out);
}

// Round 5
// 90.708 us; speedup vs baseline: 1.3697x; 1.2218x over previous
//
#include <hip/hip_runtime.h>

// Chamfer distance, B=16, N=M=4096, 2-D fp32 points, prefix-length masks.
// d_out: [fwd 16*4096][bwd 16*4096] fp32.
//
// R5: R4 post-mortem: (a) v_dot2_f32_f16 was never emitted (fallback = ~4.9
// VALU/pair from inner v_cvt), (b) occupancy ~1 wave/SIMD (random early-exit
// holes in the grid). Fixes:
//  - Packed f32: v_pk_fma_f32 is the 157-TF path. Points staged pair-packed
//    ({x0,x1},{y0,y1},{n0,n1}); per 2 points/query: 2 pk_fma + 1 min3
//    = 1.5 instr/pair, full f32 (absmax ~2e-3).
//  - Compacted dispatch: block SALU-scans the 32 row lengths, maps blockIdx
//    to the g-th ACTIVE (row, 64-pt chunk) unit -> ~1024 equal-work blocks
//    contiguous from 0 (~4/CU resident, 16 waves/CU). No memset needed:
//    inactive ws slices are never read by reduce (s >= nact).
// Zero atomics/fences (R3 lesson); plain stores + kernel-boundary ordering.

#define NQ 16
typedef float f2 __attribute__((ext_vector_type(2)));

__global__ __launch_bounds__(256, 4) void chamfer_main(
    const float* __restrict__ src, const float* __restrict__ tgt,
    const int* __restrict__ slen, const int* __restrict__ tlen,
    float* __restrict__ part)   // [32 rows][64 slices][4096] partial mins
{
    __shared__ float4 sh_xy[32];   // {x0,x1,y0,y1} per point-pair
    __shared__ f2     sh_n[32];    // {n0,n1}

    const int g   = blockIdx.x;
    const int tid = threadIdx.x;

    // Compacted work lookup: g -> (row, pc). All uniform SALU.
    int row = -1, pc = 0, Lp = 0, acc = 0;
    #pragma unroll
    for (int rr = 0; rr < 32; ++rr) {
        const int L = (rr < 16) ? tlen[rr] : slen[rr - 16];  // search-side length
        const int n = (L + 63) >> 6;                         // active 64-pt chunks
        if (row < 0 && g < acc + n) { row = rr; pc = g - acc; Lp = L; }
        acc += n;
    }
    if (row < 0) return;             // tail blocks: beyond total active units
    const int dir = row >> 4, b = row & 15;

    const float* Q = dir ? tgt : src;
    const float* P = dir ? src : tgt;

    // Stage 64 points (32 pairs), pair-packed, with poison n for idx >= Lp.
    if (tid < 32) {
        const int base = pc * 64 + tid * 2;                  // point idx in row
        const float4 pp = ((const float4*)P)[(b * 4096 + base) >> 1];  // {x0,y0,x1,y1}
        const float n0 = (base + 0 < Lp) ? fmaf(pp.x, pp.x, pp.y * pp.y) : 1e30f;
        const float n1 = (base + 1 < Lp) ? fmaf(pp.z, pp.z, pp.w * pp.w) : 1e30f;
        sh_xy[tid] = make_float4(pp.x, pp.z, pp.y, pp.w);    // {x0,x1,y0,y1}
        sh_n[tid]  = f2{n0, n1};
    }
    __syncthreads();

    // 16 queries/thread (whole 4096-query row), f32.
    f2 m2x[NQ], m2y[NQ];
    float s2[NQ], best[NQ];
    #pragma unroll
    for (int k = 0; k < NQ; ++k) {
        const float2 q = ((const float2*)Q)[b * 4096 + tid + k * 256];
        const float mx = -2.f * q.x, my = -2.f * q.y;
        m2x[k] = f2{mx, mx};
        m2y[k] = f2{my, my};
        s2[k]  = fmaf(q.x, q.x, q.y * q.y);
        best[k] = 3.0e38f;
    }

    // Per pair-of-points per query: 2 v_pk_fma_f32 + 1 v_min3_f32.
    #pragma unroll 4
    for (int j = 0; j < 32; ++j) {
        const float4 xy = sh_xy[j];
        const f2 xp = f2{xy.x, xy.y};
        const f2 yp = f2{xy.z, xy.w};
        const f2 np = sh_n[j];
        #pragma unroll
        for (int k = 0; k < NQ; ++k) {
            f2 v = m2x[k] * xp + np;      // v_pk_fma_f32: n - 2qx*tx
            v = m2y[k] * yp + v;          // v_pk_fma_f32: n - 2q.t
            best[k] = fminf(best[k], fminf(v.x, v.y));  // v_min3_f32
        }
    }

    // Plain coalesced stores to this unit's private slice. No atomics.
    float* slice = part + ((size_t)row * 64 + pc) * 4096;
    #pragma unroll
    for (int k = 0; k < NQ; ++k)
        slice[tid + k * 256] = fmaxf(best[k] + s2[k], 0.f);  // clamp commutes with min
}

__global__ __launch_bounds__(256) void chamfer_reduce(
    const float* __restrict__ part,
    const int* __restrict__ slen, const int* __restrict__ tlen,
    float* __restrict__ out)
{
    const int t  = blockIdx.x * 256 + threadIdx.x;   // 32768 threads, 4 elems each
    const int i4 = t * 4;
    const int row = i4 >> 12;                        // dir*16 + b
    const int dir = row >> 4, b = row & 15;
    const int i   = i4 & 4095;
    const int Lq = dir ? tlen[b] : slen[b];
    const int Lp = dir ? slen[b] : tlen[b];
    const int nact = (Lp + 63) >> 6;                 // active slices (block-uniform)

    float4 best = make_float4(1e10f, 1e10f, 1e10f, 1e10f);
    const float4* p = (const float4*)(part + (size_t)row * 64 * 4096 + i);
    #pragma unroll 4
    for (int s = 0; s < nact; ++s) {
        const float4 v = p[(size_t)s * 1024];        // stride 4096 floats
        best.x = fminf(best.x, v.x);
        best.y = fminf(best.y, v.y);
        best.z = fminf(best.z, v.z);
        best.w = fminf(best.w, v.w);
    }
    float4 r;
    r.x = (i + 0 < Lq) ? sqrtf(best.x) : 0.f;        // nact==0 -> sqrt(1e10), matches ref
    r.y = (i + 1 < Lq) ? sqrtf(best.y) : 0.f;
    r.z = (i + 2 < Lq) ? sqrtf(best.z) : 0.f;
    r.w = (i + 3 < Lq) ? sqrtf(best.w) : 0.f;
    ((float4*)out)[t] = r;
}

extern "C" void kernel_launch(void* const* d_in, const int* in_sizes, int n_in,
                              void* d_out, int out_size, void* d_ws, size_t ws_size,
                              hipStream_t stream) {
    const float* src = (const float*)d_in[0];   // [16,4096,2] f32
    const float* tgt = (const float*)d_in[1];   // [16,4096,2] f32
    const int* slen  = (const int*)d_in[2];     // [16] i32
    const int* tlen  = (const int*)d_in[3];     // [16] i32
    float* part = (float*)d_ws;                 // 32 x 64 x 4096 f32 = 33.5 MB

    chamfer_main<<<2048, 256, 0, stream>>>(src, tgt, slen, tlen, part);
    chamfer_reduce<<<128, 256, 0, stream>>>(part, slen, tlen, (float*)d_out);
}

// Round 6
// 84.063 us; speedup vs baseline: 1.4780x; 1.0791x over previous
//
#include <hip/hip_runtime.h>

// Chamfer distance, B=16, N=M=4096, 2-D fp32 points, prefix-length masks.
// d_out: [fwd 16*4096][bwd 16*4096] fp32.
//
// R6 (from R5 accounting): harness's 268MB ws-poison fill (~42us @ 6.2TB/s)
// is an external floor; controllable = main + reduce + gaps (~48us in R5).
//  - Point-chunk 64 -> 128: halves partial-min traffic (16.8 -> 8.4 MB each
//    way; the reduce's cross-XCD re-read was the hidden ~10us), grid ~512
//    active blocks (~2/CU, 8 waves/CU). VALU total invariant (~5us).
//  - Scalar*vector pk_fma (xp * mx[k]): op_sel broadcast, 4 state VGPR/query
//    (~90 total), launch_bounds(256,2) => no spill possible (R5 risked a
//    silent spill under the (256,4) 128-VGPR cap).
//  - Reduce: 256 blocks x 128 threads -> all 256 CUs, nact ~16 iters.
// Zero atomics/fences (R3 lesson: device-scope fence = L2 writeback per
// block on 8-XCD gfx950). Kernel boundary provides visibility.
// Math: d2 = (t2 - 2q.t) + s2 as 2 v_pk_fma_f32 + 1 v_min3_f32 per
// 2 points per query = 1.5 VALU/pair, full f32 (absmax ~2e-3).

#define NQ 16
typedef float f2 __attribute__((ext_vector_type(2)));

__global__ __launch_bounds__(256, 2) void chamfer_main(
    const float* __restrict__ src, const float* __restrict__ tgt,
    const int* __restrict__ slen, const int* __restrict__ tlen,
    float* __restrict__ part)   // [32 rows][32 slices][4096] partial mins
{
    __shared__ float4 sh_xy[64];   // {x0,x1,y0,y1} per point-pair
    __shared__ f2     sh_n[64];    // {|t0|^2, |t1|^2}

    const int g   = blockIdx.x;
    const int tid = threadIdx.x;

    // Compacted work lookup: g -> (row, pc). Uniform SALU.
    int row = -1, pc = 0, Lp = 0, acc = 0;
    #pragma unroll
    for (int rr = 0; rr < 32; ++rr) {
        const int L = (rr < 16) ? tlen[rr] : slen[rr - 16];  // search-side length
        const int n = (L + 127) >> 7;                        // active 128-pt chunks
        if (row < 0 && g < acc + n) { row = rr; pc = g - acc; Lp = L; }
        acc += n;
    }
    if (row < 0) return;             // beyond total active units
    const int dir = row >> 4, b = row & 15;

    const float* Q = dir ? tgt : src;
    const float* P = dir ? src : tgt;

    // Stage 128 points (64 pairs), pair-packed; poison n for idx >= Lp.
    if (tid < 64) {
        const int base = pc * 128 + tid * 2;
        const float4 pp = ((const float4*)P)[(b * 4096 + base) >> 1];  // {x0,y0,x1,y1}
        const float n0 = (base + 0 < Lp) ? fmaf(pp.x, pp.x, pp.y * pp.y) : 1e30f;
        const float n1 = (base + 1 < Lp) ? fmaf(pp.z, pp.z, pp.w * pp.w) : 1e30f;
        sh_xy[tid] = make_float4(pp.x, pp.z, pp.y, pp.w);    // {x0,x1,y0,y1}
        sh_n[tid]  = f2{n0, n1};
    }
    __syncthreads();

    // 16 queries/thread (whole 4096-query row). 4 state VGPRs per query.
    float mx[NQ], my[NQ], s2[NQ], best[NQ];
    #pragma unroll
    for (int k = 0; k < NQ; ++k) {
        const float2 q = ((const float2*)Q)[b * 4096 + tid + k * 256];
        mx[k] = -2.f * q.x;
        my[k] = -2.f * q.y;
        s2[k] = fmaf(q.x, q.x, q.y * q.y);
        best[k] = 3.0e38f;
    }

    // Per point-pair per query: 2 v_pk_fma_f32 (scalar op_sel broadcast)
    // + 1 v_min3_f32. 16 independent dep chains -> full issue rate.
    #pragma unroll 4
    for (int j = 0; j < 64; ++j) {
        const float4 xy = sh_xy[j];
        const f2 xp = f2{xy.x, xy.y};
        const f2 yp = f2{xy.z, xy.w};
        const f2 np = sh_n[j];
        #pragma unroll
        for (int k = 0; k < NQ; ++k) {
            f2 v = xp * mx[k] + np;       // pk_fma: n - 2qx*tx
            v = yp * my[k] + v;           // pk_fma: n - 2q.t
            best[k] = fminf(best[k], fminf(v.x, v.y));  // v_min3_f32
        }
    }

    // Plain coalesced stores to this unit's private slice. No atomics.
    float* slice = part + ((size_t)row * 32 + pc) * 4096;
    #pragma unroll
    for (int k = 0; k < NQ; ++k)
        slice[tid + k * 256] = fmaxf(best[k] + s2[k], 0.f);  // clamp commutes with min
}

__global__ __launch_bounds__(128) void chamfer_reduce(
    const float* __restrict__ part,
    const int* __restrict__ slen, const int* __restrict__ tlen,
    float* __restrict__ out)
{
    const int t  = blockIdx.x * 128 + threadIdx.x;   // 32768 threads, 4 elems each
    const int i4 = t * 4;
    const int row = i4 >> 12;                        // dir*16 + b
    const int dir = row >> 4, b = row & 15;
    const int i   = i4 & 4095;
    const int Lq = dir ? tlen[b] : slen[b];
    const int Lp = dir ? slen[b] : tlen[b];
    const int nact = (Lp + 127) >> 7;                // active slices (block-uniform)

    float4 best = make_float4(1e10f, 1e10f, 1e10f, 1e10f);
    const float4* p = (const float4*)(part + (size_t)row * 32 * 4096 + i);
    #pragma unroll 4
    for (int s = 0; s < nact; ++s) {
        const float4 v = p[(size_t)s * 1024];        // stride 4096 floats
        best.x = fminf(best.x, v.x);
        best.y = fminf(best.y, v.y);
        best.z = fminf(best.z, v.z);
        best.w = fminf(best.w, v.w);
    }
    float4 r;
    r.x = (i + 0 < Lq) ? sqrtf(best.x) : 0.f;        // nact==0 -> sqrt(1e10), matches ref
    r.y = (i + 1 < Lq) ? sqrtf(best.y) : 0.f;
    r.z = (i + 2 < Lq) ? sqrtf(best.z) : 0.f;
    r.w = (i + 3 < Lq) ? sqrtf(best.w) : 0.f;
    ((float4*)out)[t] = r;
}

extern "C" void kernel_launch(void* const* d_in, const int* in_sizes, int n_in,
                              void* d_out, int out_size, void* d_ws, size_t ws_size,
                              hipStream_t stream) {
    const float* src = (const float*)d_in[0];   // [16,4096,2] f32
    const float* tgt = (const float*)d_in[1];   // [16,4096,2] f32
    const int* slen  = (const int*)d_in[2];     // [16] i32
    const int* tlen  = (const int*)d_in[3];     // [16] i32
    float* part = (float*)d_ws;                 // 32 x 32 x 4096 f32 = 16.8 MB

    chamfer_main<<<1024, 256, 0, stream>>>(src, tgt, slen, tlen, part);
    chamfer_reduce<<<256, 128, 0, stream>>>(part, slen, tlen, (float*)d_out);
}